// Round 1
// baseline (484.805 us; speedup 1.0000x reference)
//
#include <hip/hip_runtime.h>

#define NJ 24
#define EPSF 1e-8f

static __device__ __forceinline__ int parent_of(int i) {
    constexpr int P[NJ] = {-1, 0, 0, 0, 1, 2, 3, 4, 5, 6, 7, 8, 9, 9, 9, 12, 13, 14, 16, 17, 18, 19, 20, 21};
    return P[i];
}

// Rodrigues matrix from raw axis + angle_u (matches reference's double-normalize).
static __device__ __forceinline__ void make_Ra(float ax, float ay, float az, float au, float R[9]) {
    float n1 = sqrtf(ax*ax + ay*ay + az*az) + EPSF;
    ax /= n1; ay /= n1; az /= n1;
    float n2 = sqrtf(ax*ax + ay*ay + az*az) + EPSF;   // reference normalizes twice
    ax /= n2; ay /= n2; az /= n2;
    float ang = (au * 2.0f - 1.0f) * 0.2f;
    float c = cosf(ang), s = sinf(ang), oc = 1.0f - c;
    R[0] = 1.0f + oc*(ax*ax - 1.0f); R[1] = -s*az + oc*ax*ay;        R[2] =  s*ay + oc*ax*az;
    R[3] =  s*az + oc*ax*ay;         R[4] = 1.0f + oc*(ay*ay - 1.0f); R[5] = -s*ax + oc*ay*az;
    R[6] = -s*ay + oc*ax*az;         R[7] =  s*ax + oc*ay*az;         R[8] = 1.0f + oc*(az*az - 1.0f);
}

// ================== Fused kernel: chain + camera + rots + projection ==================
// One wave per block, 64 elements per block.
// stg  : poses-in staging is NOT here (goes via rbuf); stg holds AXIS resident through
//        chain + rots phases, then is reused for poses-out and 2d-out staging.
// rbuf : poses-in staging, then rot_mats chunks (8 joints = 72 floats/elem per chunk).
// Both use the stride-73 transpose trick (73 coprime with 32 banks -> 2-way max, free).
__global__ __launch_bounds__(64)
void poseaug_fused_kernel(const float* __restrict__ poses_3d,
                          const float* __restrict__ rot_mats,
                          const float* __restrict__ axis,
                          const float* __restrict__ angle_u,
                          const float* __restrict__ scale_u,
                          const float* __restrict__ Kin,
                          const float* __restrict__ Rin,
                          const float* __restrict__ tin,
                          const float* __restrict__ focal_u,
                          const float* __restrict__ yaw_u,
                          const float* __restrict__ pitch_u,
                          const float* __restrict__ t_jit,
                          float* __restrict__ out, int B)
{
    __shared__ __align__(16) float stg[64 * 73];    // 18688 B
    __shared__ __align__(16) float rbuf[64 * 73];   // 18688 B  (total 37376 B -> 4 blocks/CU)
    const int l  = threadIdx.x;
    const int e0 = blockIdx.x * 64;
    const int n  = min(64, B - e0);
    const int b  = e0 + l;
    const bool act = (b < B);

    float* out_poses = out;
    float* out_2d    = out + (size_t)B * 72;
    float* out_rots  = out + (size_t)B * 120;
    float* out_K     = out + (size_t)B * 336;
    float* out_R     = out + (size_t)B * 345;
    float* out_t     = out + (size_t)B * 354;

    // ---- stage poses -> rbuf AND axis -> stg (both load streams in flight) ----
    {
        const float* gp = poses_3d + (size_t)e0 * 72;
        const float* ga = axis     + (size_t)e0 * 72;
        if (n == 64) {
            const float4* gp4 = (const float4*)gp;
            const float4* ga4 = (const float4*)ga;
            #pragma unroll
            for (int it = 0; it < 18; ++it) {
                int i4 = l + it * 64;
                float4 vp = gp4[i4];
                float4 va = ga4[i4];
                int o = i4 * 4;
                int base = (o / 72) * 73 + (o % 72);
                rbuf[base] = vp.x; rbuf[base+1] = vp.y; rbuf[base+2] = vp.z; rbuf[base+3] = vp.w;
                stg[base]  = va.x; stg[base+1]  = va.y; stg[base+2]  = va.z; stg[base+3]  = va.w;
            }
        } else {
            for (int o = l; o < n * 72; o += 64) {
                int base = (o / 72) * 73 + (o % 72);
                rbuf[base] = gp[o];
                stg[base]  = ga[o];
            }
        }
    }
    __syncthreads();
    float pf[72];
    #pragma unroll
    for (int k = 0; k < 72; ++k) pf[k] = rbuf[l * 73 + k];
    // (rbuf reads complete before the rots chunk loop's leading __syncthreads)

    // ---- angle/scale: back-to-back float4 loads into registers ----
    float au[24], su[24];
    if (act) {
        const float4* ga = (const float4*)(angle_u + (size_t)b * 24);
        const float4* gs = (const float4*)(scale_u + (size_t)b * 24);
        #pragma unroll
        for (int q = 0; q < 6; ++q) {
            float4 va = ga[q]; au[4*q+0]=va.x; au[4*q+1]=va.y; au[4*q+2]=va.z; au[4*q+3]=va.w;
            float4 vs = gs[q]; su[4*q+0]=vs.x; su[4*q+1]=vs.y; su[4*q+2]=vs.z; su[4*q+3]=vs.w;
        }
    }

    // ---- kinematic chain (axis read from stg, resident) ----
    #pragma unroll
    for (int i = 1; i < NJ; ++i) {
        const int par = parent_of(i);
        float bx = pf[3*i+0] - pf[3*par+0];
        float by = pf[3*i+1] - pf[3*par+1];
        float bz = pf[3*i+2] - pf[3*par+2];
        float blen = sqrtf(bx*bx + by*by + bz*bz);

        float Ra[9];
        make_Ra(stg[l*73 + 3*i + 0], stg[l*73 + 3*i + 1], stg[l*73 + 3*i + 2], au[i], Ra);

        float rbx = Ra[0]*bx + Ra[1]*by + Ra[2]*bz;
        float rby = Ra[3]*bx + Ra[4]*by + Ra[5]*bz;
        float rbz = Ra[6]*bx + Ra[7]*by + Ra[8]*bz;

        float scale = 1.0f + (su[i] * 2.0f - 1.0f) * 0.1f;
        float rn = sqrtf(rbx*rbx + rby*rby + rbz*rbz) + EPSF;
        float f = scale * blen / rn;

        pf[3*i+0] = pf[3*par+0] + rbx * f;
        pf[3*i+1] = pf[3*par+1] + rby * f;
        pf[3*i+2] = pf[3*par+2] + rbz * f;
    }

    // ---- camera (direct loads/stores; small contiguous segments) ----
    float K00, K02, K11, K12;
    float A[9], tx = 0.f, ty = 0.f, tz = 0.f;
    if (act) {
        float Kf[9];
        const float* kb = Kin + (size_t)b * 9;
        const float* rb = Rin + (size_t)b * 9;
        #pragma unroll
        for (int k = 0; k < 9; ++k) Kf[k] = kb[k];
        float f0 = focal_u[(size_t)b*2+0], f1 = focal_u[(size_t)b*2+1];
        Kf[0] *= 1.0f + (f0*2.0f - 1.0f) * 0.01f;
        Kf[4] *= 1.0f + (f1*2.0f - 1.0f) * 0.01f;
        K00 = Kf[0]; K02 = Kf[2]; K11 = Kf[4]; K12 = Kf[5];

        float yaw   = (yaw_u[b]   * 2.0f - 1.0f) * 0.01f;
        float pitch = (pitch_u[b] * 2.0f - 1.0f) * 0.005f;
        float cy = cosf(yaw),  sy = sinf(yaw);
        float cp = cosf(pitch), sp = sinf(pitch);
        float M00 = cy,   M01 = sy*sp, M02 = sy*cp;
        float M11 = cp,   M12 = -sp;
        float M20 = -sy,  M21 = cy*sp, M22 = cy*cp;

        float R00=rb[0],R01=rb[1],R02=rb[2],R10=rb[3],R11=rb[4],R12=rb[5],R20=rb[6],R21=rb[7],R22=rb[8];
        A[0] = R00*M00 + R02*M20; A[1] = R00*M01 + R01*M11 + R02*M21; A[2] = R00*M02 + R01*M12 + R02*M22;
        A[3] = R10*M00 + R12*M20; A[4] = R10*M01 + R11*M11 + R12*M21; A[5] = R10*M02 + R11*M12 + R12*M22;
        A[6] = R20*M00 + R22*M20; A[7] = R20*M01 + R21*M11 + R22*M21; A[8] = R20*M02 + R21*M12 + R22*M22;

        tx = tin[(size_t)b*3+0] + t_jit[(size_t)b*3+0] * 0.005f;
        ty = tin[(size_t)b*3+1] + t_jit[(size_t)b*3+1] * 0.005f;
        tz = tin[(size_t)b*3+2] + t_jit[(size_t)b*3+2] * 0.005f;

        float* ok = out_K + (size_t)b * 9;
        #pragma unroll
        for (int k = 0; k < 9; ++k) ok[k] = Kf[k];
        float* orr = out_R + (size_t)b * 9;
        #pragma unroll
        for (int k = 0; k < 9; ++k) orr[k] = A[k];
        float* ot = out_t + (size_t)b * 3;
        ot[0] = tx; ot[1] = ty; ot[2] = tz;
    }

    // ---- rots = rot_mats @ Ra, fused: 3 chunks of 8 joints via rbuf ----
    // axis still resident in stg; au[] still in registers -> zero extra HBM reads.
    #pragma unroll
    for (int c = 0; c < 3; ++c) {
        __syncthreads();   // rbuf free (pf reads / previous chunk's store done)
        const float* gld = rot_mats + (size_t)e0 * 216 + 72 * c;
        if (n == 64) {
            #pragma unroll
            for (int it = 0; it < 18; ++it) {
                int f = it * 64 + l;               // flat float4 index in [0,1152)
                int r = f / 18;                    // element row
                int k = (f % 18) * 4;              // dword offset within the 72-float chunk
                const float4 v = *(const float4*)(gld + (size_t)r * 216 + k);
                int base = r * 73 + k;
                rbuf[base] = v.x; rbuf[base+1] = v.y; rbuf[base+2] = v.z; rbuf[base+3] = v.w;
            }
        } else {
            for (int o = l; o < n * 72; o += 64)
                rbuf[(o/72)*73 + (o%72)] = gld[(size_t)(o/72)*216 + (o%72)];
        }
        __syncthreads();
        if (act) {
            #pragma unroll
            for (int jj = 0; jj < 8; ++jj) {
                const int j = c * 8 + jj;          // compile-time (both loops unrolled)
                float m[9];
                #pragma unroll
                for (int q = 0; q < 9; ++q) m[q] = rbuf[l*73 + 9*jj + q];
                float r9[9];
                if (j == 0) {
                    #pragma unroll
                    for (int q = 0; q < 9; ++q) r9[q] = m[q];
                } else {
                    float Ra[9];
                    make_Ra(stg[l*73 + 3*j + 0], stg[l*73 + 3*j + 1], stg[l*73 + 3*j + 2], au[j], Ra);
                    r9[0] = m[0]*Ra[0] + m[1]*Ra[3] + m[2]*Ra[6];
                    r9[1] = m[0]*Ra[1] + m[1]*Ra[4] + m[2]*Ra[7];
                    r9[2] = m[0]*Ra[2] + m[1]*Ra[5] + m[2]*Ra[8];
                    r9[3] = m[3]*Ra[0] + m[4]*Ra[3] + m[5]*Ra[6];
                    r9[4] = m[3]*Ra[1] + m[4]*Ra[4] + m[5]*Ra[7];
                    r9[5] = m[3]*Ra[2] + m[4]*Ra[5] + m[5]*Ra[8];
                    r9[6] = m[6]*Ra[0] + m[7]*Ra[3] + m[8]*Ra[6];
                    r9[7] = m[6]*Ra[1] + m[7]*Ra[4] + m[8]*Ra[7];
                    r9[8] = m[6]*Ra[2] + m[7]*Ra[5] + m[8]*Ra[8];
                }
                #pragma unroll
                for (int q = 0; q < 9; ++q) rbuf[l*73 + 9*jj + q] = r9[q];
            }
        }
        __syncthreads();
        float* gst = out_rots + (size_t)e0 * 216 + 72 * c;
        if (n == 64) {
            #pragma unroll
            for (int it = 0; it < 18; ++it) {
                int f = it * 64 + l;
                int r = f / 18;
                int k = (f % 18) * 4;
                int base = r * 73 + k;
                *(float4*)(gst + (size_t)r * 216 + k) =
                    make_float4(rbuf[base], rbuf[base+1], rbuf[base+2], rbuf[base+3]);
            }
        } else {
            for (int o = l; o < n * 72; o += 64)
                gst[(size_t)(o/72)*216 + (o%72)] = rbuf[(o/72)*73 + (o%72)];
        }
    }

    // ---- store poses via LDS transpose (stg: axis dead now) ----
    __syncthreads();
    #pragma unroll
    for (int k = 0; k < 72; ++k) stg[l * 73 + k] = pf[k];
    __syncthreads();
    {
        float* g = out_poses + (size_t)e0 * 72;
        if (n == 64) {
            float4* g4 = (float4*)g;
            #pragma unroll
            for (int it = 0; it < 18; ++it) {
                int i4 = l + it * 64;
                int o = i4 * 4;
                int base = (o / 72) * 73 + (o % 72);
                g4[i4] = make_float4(stg[base], stg[base+1], stg[base+2], stg[base+3]);
            }
        } else {
            for (int o = l; o < n * 72; o += 64) g[o] = stg[(o / 72) * 73 + (o % 72)];
        }
    }

    // ---- projection -> LDS -> coalesced store ----
    __syncthreads();
    if (act) {
        #pragma unroll
        for (int j = 0; j < NJ; ++j) {
            float px = pf[3*j+0], py = pf[3*j+1], pz = pf[3*j+2];
            float cx = A[0]*px + A[1]*py + A[2]*pz + tx;
            float cv = A[3]*px + A[4]*py + A[5]*pz + ty;
            float cz = A[6]*px + A[7]*py + A[8]*pz + tz;
            float zc = fmaxf(cz, 1e-5f);
            stg[l*73 + 2*j + 0] = (K00 * (cx / zc) + K02) * (2.0f / 512.0f) - 1.0f;
            stg[l*73 + 2*j + 1] = (K11 * (cv / zc) + K12) * (2.0f / 512.0f) - 1.0f;
        }
    }
    __syncthreads();
    {
        float* g = out_2d + (size_t)e0 * 48;
        if (n == 64) {
            float4* g4 = (float4*)g;
            #pragma unroll
            for (int it = 0; it < 12; ++it) {
                int i4 = l + it * 64;
                int o = i4 * 4;
                int base = (o / 48) * 73 + (o % 48);
                g4[i4] = make_float4(stg[base], stg[base+1], stg[base+2], stg[base+3]);
            }
        } else {
            for (int o = l; o < n * 48; o += 64) g[o] = stg[(o / 48) * 73 + (o % 48)];
        }
    }
}

extern "C" void kernel_launch(void* const* d_in, const int* in_sizes, int n_in,
                              void* d_out, int out_size, void* d_ws, size_t ws_size,
                              hipStream_t stream) {
    const float* poses_3d = (const float*)d_in[0];
    const float* rot_mats = (const float*)d_in[1];
    const float* axis     = (const float*)d_in[2];
    const float* angle_u  = (const float*)d_in[3];
    const float* scale_u  = (const float*)d_in[4];
    const float* Kin      = (const float*)d_in[5];
    const float* Rin      = (const float*)d_in[6];
    const float* tin      = (const float*)d_in[7];
    const float* focal_u  = (const float*)d_in[8];
    const float* yaw_u    = (const float*)d_in[9];
    const float* pitch_u  = (const float*)d_in[10];
    const float* t_jit    = (const float*)d_in[11];
    float* out = (float*)d_out;

    const int B = in_sizes[9];   // yaw_u is (B,)

    dim3 blk(64), grd((B + 63) / 64);
    hipLaunchKernelGGL(poseaug_fused_kernel, grd, blk, 0, stream,
                       poses_3d, rot_mats, axis, angle_u, scale_u, Kin, Rin, tin,
                       focal_u, yaw_u, pitch_u, t_jit, out, B);
}

// Round 2
// 424.693 us; speedup vs baseline: 1.1415x; 1.1415x over previous
//
#include <hip/hip_runtime.h>

#define NJ 24
#define EPSF 1e-8f

static __device__ __forceinline__ int parent_of(int i) {
    constexpr int P[NJ] = {-1, 0, 0, 0, 1, 2, 3, 4, 5, 6, 7, 8, 9, 9, 9, 12, 13, 14, 16, 17, 18, 19, 20, 21};
    return P[i];
}

// Rodrigues matrix from raw axis + angle_u (matches reference's double-normalize).
static __device__ __forceinline__ void make_Ra(float ax, float ay, float az, float au, float R[9]) {
    float n1 = sqrtf(ax*ax + ay*ay + az*az) + EPSF;
    ax /= n1; ay /= n1; az /= n1;
    float n2 = sqrtf(ax*ax + ay*ay + az*az) + EPSF;   // reference normalizes twice
    ax /= n2; ay /= n2; az /= n2;
    float ang = (au * 2.0f - 1.0f) * 0.2f;
    float c = cosf(ang), s = sinf(ang), oc = 1.0f - c;
    R[0] = 1.0f + oc*(ax*ax - 1.0f); R[1] = -s*az + oc*ax*ay;        R[2] =  s*ay + oc*ax*az;
    R[3] =  s*az + oc*ax*ay;         R[4] = 1.0f + oc*(ay*ay - 1.0f); R[5] = -s*ax + oc*ay*az;
    R[6] = -s*ay + oc*ax*az;         R[7] =  s*ax + oc*ay*az;         R[8] = 1.0f + oc*(az*az - 1.0f);
}

// ================== Fused kernel v2: single 18.7 KB LDS buffer ==================
// Grid = B/64 = 2048 blocks -> 8 blocks/CU max (grid-capped). LDS <= 20 KB keeps
// us at that cap; VGPR budget 256 (__launch_bounds__(64,2)) for 2 waves/SIMD.
// Chain + rots fused per 8-joint chunk: Ra computed ONCE per joint.
// poses-in / axis / angle / scale: direct per-thread float4 loads (lane-private
// 288-B records, L1-absorbed, every byte consumed -> no HBM over-fetch).
// rot_mats in/out + poses-out + 2d-out: LDS stride-73 transpose (73 coprime 32
// banks -> 2-way max on the per-lane row accesses = free).
__global__ __launch_bounds__(64, 2)
void poseaug_fused2_kernel(const float* __restrict__ poses_3d,
                           const float* __restrict__ rot_mats,
                           const float* __restrict__ axis,
                           const float* __restrict__ angle_u,
                           const float* __restrict__ scale_u,
                           const float* __restrict__ Kin,
                           const float* __restrict__ Rin,
                           const float* __restrict__ tin,
                           const float* __restrict__ focal_u,
                           const float* __restrict__ yaw_u,
                           const float* __restrict__ pitch_u,
                           const float* __restrict__ t_jit,
                           float* __restrict__ out, int B)
{
    __shared__ __align__(16) float rbuf[64 * 73];   // 18688 B -> 8 blocks/CU (LDS-wise)
    const int l  = threadIdx.x;
    const int e0 = blockIdx.x * 64;
    const int n  = min(64, B - e0);
    const int b  = e0 + l;
    const bool act = (b < B);

    float* out_poses = out;
    float* out_2d    = out + (size_t)B * 72;
    float* out_rots  = out + (size_t)B * 120;
    float* out_K     = out + (size_t)B * 336;
    float* out_R     = out + (size_t)B * 345;
    float* out_t     = out + (size_t)B * 354;

    float pf[72];

    // ==== chunk loop: 3 chunks x 8 joints; chain + rots share one Ra ====
    #pragma unroll
    for (int c = 0; c < 3; ++c) {
        float axl[24], au8[8], su8[8];
        if (act) {
            const float4* gp = (const float4*)(poses_3d + (size_t)b * 72 + 24 * c);
            const float4* ga = (const float4*)(axis     + (size_t)b * 72 + 24 * c);
            #pragma unroll
            for (int q = 0; q < 6; ++q) {
                float4 vp = gp[q];
                pf[24*c + 4*q + 0] = vp.x; pf[24*c + 4*q + 1] = vp.y;
                pf[24*c + 4*q + 2] = vp.z; pf[24*c + 4*q + 3] = vp.w;
                float4 va = ga[q];
                axl[4*q+0] = va.x; axl[4*q+1] = va.y; axl[4*q+2] = va.z; axl[4*q+3] = va.w;
            }
            const float4* gau = (const float4*)(angle_u + (size_t)b * 24 + 8 * c);
            const float4* gsu = (const float4*)(scale_u + (size_t)b * 24 + 8 * c);
            float4 a0 = gau[0], a1 = gau[1];
            au8[0]=a0.x; au8[1]=a0.y; au8[2]=a0.z; au8[3]=a0.w;
            au8[4]=a1.x; au8[5]=a1.y; au8[6]=a1.z; au8[7]=a1.w;
            float4 s0 = gsu[0], s1 = gsu[1];
            su8[0]=s0.x; su8[1]=s0.y; su8[2]=s0.z; su8[3]=s0.w;
            su8[4]=s1.x; su8[5]=s1.y; su8[6]=s1.z; su8[7]=s1.w;
        }

        __syncthreads();   // rbuf free (previous chunk's store reads done)
        // ---- stage rot_mats chunk (8 joints = 72 floats/elem), coalesced ----
        const float* gld = rot_mats + (size_t)e0 * 216 + 72 * c;
        if (n == 64) {
            #pragma unroll
            for (int it = 0; it < 18; ++it) {
                int f = it * 64 + l;               // flat float4 index in [0,1152)
                int r = f / 18;                    // element row
                int k = (f - r * 18) * 4;          // float offset within chunk
                const float4 v = *(const float4*)(gld + (size_t)r * 216 + k);
                int base = r * 73 + k;
                rbuf[base+0] = v.x; rbuf[base+1] = v.y; rbuf[base+2] = v.z; rbuf[base+3] = v.w;
            }
        } else {
            for (int o = l; o < n * 72; o += 64)
                rbuf[(o/72)*73 + (o%72)] = gld[(size_t)(o/72)*216 + (o%72)];
        }
        __syncthreads();

        // ---- compute: chain step + rots product, Ra computed once ----
        if (act) {
            #pragma unroll
            for (int jj = 0; jj < 8; ++jj) {
                const int j = 8 * c + jj;
                float m[9];
                #pragma unroll
                for (int q = 0; q < 9; ++q) m[q] = rbuf[l*73 + 9*jj + q];
                float r9[9];
                if (j == 0) {
                    #pragma unroll
                    for (int q = 0; q < 9; ++q) r9[q] = m[q];
                } else {
                    float Ra[9];
                    make_Ra(axl[3*jj+0], axl[3*jj+1], axl[3*jj+2], au8[jj], Ra);

                    // chain step (pf[j] still original; pf[parent] already updated)
                    const int par = parent_of(j);
                    float bx = pf[3*j+0] - pf[3*par+0];
                    float by = pf[3*j+1] - pf[3*par+1];
                    float bz = pf[3*j+2] - pf[3*par+2];
                    float blen = sqrtf(bx*bx + by*by + bz*bz);
                    float rbx = Ra[0]*bx + Ra[1]*by + Ra[2]*bz;
                    float rby = Ra[3]*bx + Ra[4]*by + Ra[5]*bz;
                    float rbz = Ra[6]*bx + Ra[7]*by + Ra[8]*bz;
                    float scale = 1.0f + (su8[jj] * 2.0f - 1.0f) * 0.1f;
                    float rn = sqrtf(rbx*rbx + rby*rby + rbz*rbz) + EPSF;
                    float fsc = scale * blen / rn;
                    pf[3*j+0] = pf[3*par+0] + rbx * fsc;
                    pf[3*j+1] = pf[3*par+1] + rby * fsc;
                    pf[3*j+2] = pf[3*par+2] + rbz * fsc;

                    // rots = m @ Ra (same expression order as verified kernel)
                    r9[0] = m[0]*Ra[0] + m[1]*Ra[3] + m[2]*Ra[6];
                    r9[1] = m[0]*Ra[1] + m[1]*Ra[4] + m[2]*Ra[7];
                    r9[2] = m[0]*Ra[2] + m[1]*Ra[5] + m[2]*Ra[8];
                    r9[3] = m[3]*Ra[0] + m[4]*Ra[3] + m[5]*Ra[6];
                    r9[4] = m[3]*Ra[1] + m[4]*Ra[4] + m[5]*Ra[7];
                    r9[5] = m[3]*Ra[2] + m[4]*Ra[5] + m[5]*Ra[8];
                    r9[6] = m[6]*Ra[0] + m[7]*Ra[3] + m[8]*Ra[6];
                    r9[7] = m[6]*Ra[1] + m[7]*Ra[4] + m[8]*Ra[7];
                    r9[8] = m[6]*Ra[2] + m[7]*Ra[5] + m[8]*Ra[8];
                }
                #pragma unroll
                for (int q = 0; q < 9; ++q) rbuf[l*73 + 9*jj + q] = r9[q];
            }
        }
        __syncthreads();

        // ---- store rots chunk, coalesced ----
        float* gst = out_rots + (size_t)e0 * 216 + 72 * c;
        if (n == 64) {
            #pragma unroll
            for (int it = 0; it < 18; ++it) {
                int f = it * 64 + l;
                int r = f / 18;
                int k = (f - r * 18) * 4;
                int base = r * 73 + k;
                *(float4*)(gst + (size_t)r * 216 + k) =
                    make_float4(rbuf[base], rbuf[base+1], rbuf[base+2], rbuf[base+3]);
            }
        } else {
            for (int o = l; o < n * 72; o += 64)
                gst[(size_t)(o/72)*216 + (o%72)] = rbuf[(o/72)*73 + (o%72)];
        }
    }

    // ==== camera ====
    float K00, K02, K11, K12;
    float A[9], tx = 0.f, ty = 0.f, tz = 0.f;
    if (act) {
        float Kf[9];
        const float* kb = Kin + (size_t)b * 9;
        const float* rb = Rin + (size_t)b * 9;
        #pragma unroll
        for (int k = 0; k < 9; ++k) Kf[k] = kb[k];
        float f0 = focal_u[(size_t)b*2+0], f1 = focal_u[(size_t)b*2+1];
        Kf[0] *= 1.0f + (f0*2.0f - 1.0f) * 0.01f;
        Kf[4] *= 1.0f + (f1*2.0f - 1.0f) * 0.01f;
        K00 = Kf[0]; K02 = Kf[2]; K11 = Kf[4]; K12 = Kf[5];

        float yaw   = (yaw_u[b]   * 2.0f - 1.0f) * 0.01f;
        float pitch = (pitch_u[b] * 2.0f - 1.0f) * 0.005f;
        float cy = cosf(yaw),  sy = sinf(yaw);
        float cp = cosf(pitch), sp = sinf(pitch);
        float M00 = cy,   M01 = sy*sp, M02 = sy*cp;
        float M11 = cp,   M12 = -sp;
        float M20 = -sy,  M21 = cy*sp, M22 = cy*cp;

        float R00=rb[0],R01=rb[1],R02=rb[2],R10=rb[3],R11=rb[4],R12=rb[5],R20=rb[6],R21=rb[7],R22=rb[8];
        A[0] = R00*M00 + R02*M20; A[1] = R00*M01 + R01*M11 + R02*M21; A[2] = R00*M02 + R01*M12 + R02*M22;
        A[3] = R10*M00 + R12*M20; A[4] = R10*M01 + R11*M11 + R12*M21; A[5] = R10*M02 + R11*M12 + R12*M22;
        A[6] = R20*M00 + R22*M20; A[7] = R20*M01 + R21*M11 + R22*M21; A[8] = R20*M02 + R21*M12 + R22*M22;

        tx = tin[(size_t)b*3+0] + t_jit[(size_t)b*3+0] * 0.005f;
        ty = tin[(size_t)b*3+1] + t_jit[(size_t)b*3+1] * 0.005f;
        tz = tin[(size_t)b*3+2] + t_jit[(size_t)b*3+2] * 0.005f;

        float* ok = out_K + (size_t)b * 9;
        #pragma unroll
        for (int k = 0; k < 9; ++k) ok[k] = Kf[k];
        float* orr = out_R + (size_t)b * 9;
        #pragma unroll
        for (int k = 0; k < 9; ++k) orr[k] = A[k];
        float* ot = out_t + (size_t)b * 3;
        ot[0] = tx; ot[1] = ty; ot[2] = tz;
    }

    // ==== projection -> LDS -> coalesced store ====
    __syncthreads();   // rbuf free (last rot chunk store done)
    if (act) {
        #pragma unroll
        for (int j = 0; j < NJ; ++j) {
            float px = pf[3*j+0], py = pf[3*j+1], pz = pf[3*j+2];
            float cx = A[0]*px + A[1]*py + A[2]*pz + tx;
            float cv = A[3]*px + A[4]*py + A[5]*pz + ty;
            float cz = A[6]*px + A[7]*py + A[8]*pz + tz;
            float zc = fmaxf(cz, 1e-5f);
            rbuf[l*73 + 2*j + 0] = (K00 * (cx / zc) + K02) * (2.0f / 512.0f) - 1.0f;
            rbuf[l*73 + 2*j + 1] = (K11 * (cv / zc) + K12) * (2.0f / 512.0f) - 1.0f;
        }
    }
    __syncthreads();
    {
        float* g = out_2d + (size_t)e0 * 48;
        if (n == 64) {
            float4* g4 = (float4*)g;
            #pragma unroll
            for (int it = 0; it < 12; ++it) {
                int i4 = l + it * 64;
                int o = i4 * 4;
                int base = (o / 48) * 73 + (o % 48);
                g4[i4] = make_float4(rbuf[base], rbuf[base+1], rbuf[base+2], rbuf[base+3]);
            }
        } else {
            for (int o = l; o < n * 48; o += 64) g[o] = rbuf[(o / 48) * 73 + (o % 48)];
        }
    }

    // ==== poses out via LDS transpose ====
    __syncthreads();
    if (act) {
        #pragma unroll
        for (int k = 0; k < 72; ++k) rbuf[l * 73 + k] = pf[k];
    }
    __syncthreads();
    {
        float* g = out_poses + (size_t)e0 * 72;
        if (n == 64) {
            float4* g4 = (float4*)g;
            #pragma unroll
            for (int it = 0; it < 18; ++it) {
                int i4 = l + it * 64;
                int o = i4 * 4;
                int base = (o / 72) * 73 + (o % 72);
                g4[i4] = make_float4(rbuf[base], rbuf[base+1], rbuf[base+2], rbuf[base+3]);
            }
        } else {
            for (int o = l; o < n * 72; o += 64) g[o] = rbuf[(o / 72) * 73 + (o % 72)];
        }
    }
}

extern "C" void kernel_launch(void* const* d_in, const int* in_sizes, int n_in,
                              void* d_out, int out_size, void* d_ws, size_t ws_size,
                              hipStream_t stream) {
    const float* poses_3d = (const float*)d_in[0];
    const float* rot_mats = (const float*)d_in[1];
    const float* axis     = (const float*)d_in[2];
    const float* angle_u  = (const float*)d_in[3];
    const float* scale_u  = (const float*)d_in[4];
    const float* Kin      = (const float*)d_in[5];
    const float* Rin      = (const float*)d_in[6];
    const float* tin      = (const float*)d_in[7];
    const float* focal_u  = (const float*)d_in[8];
    const float* yaw_u    = (const float*)d_in[9];
    const float* pitch_u  = (const float*)d_in[10];
    const float* t_jit    = (const float*)d_in[11];
    float* out = (float*)d_out;

    const int B = in_sizes[9];   // yaw_u is (B,)

    dim3 blk(64), grd((B + 63) / 64);
    hipLaunchKernelGGL(poseaug_fused2_kernel, grd, blk, 0, stream,
                       poses_3d, rot_mats, axis, angle_u, scale_u, Kin, Rin, tin,
                       focal_u, yaw_u, pitch_u, t_jit, out, B);
}